// Round 6
// baseline (161.352 us; speedup 1.0000x reference)
//
#include <hip/hip_runtime.h>

// Problem constants (match reference)
constexpr int N     = 8192;     // nodes
constexpr int NE    = 131072;   // edges
constexpr int WPR   = N / 32;   // 256 u32 words per bitset row
constexpr int MAXD  = 64;       // max distinct out-degree (actual max ~45)
constexpr int MAXP2 = 1024;     // max stored |P2 row| as u16 ids (actual ~250, tail <~700)

// f(k) = exp(-ALPHA*k), ALPHA = 2
#define F1 0.13533528323661270f   // e^-2
#define F2 0.018315638888734179f  // e^-4
#define F3 0.0024787521766663585f // e^-6

// ---------------------------------------------------------------------------
// Fused MLP: angles = relu(relu(relu(X@W0)@W1)@W2) @ W3.  (unchanged from R5)
// ---------------------------------------------------------------------------
__global__ __launch_bounds__(256) void mlp_kernel(
    const float* __restrict__ X,
    const float* __restrict__ W0, const float* __restrict__ W1,
    const float* __restrict__ W2, const float* __restrict__ W3,
    float* __restrict__ angles)
{
    __shared__ float Xs[32 * 132];   // padded stride 132
    __shared__ float Ws[64 * 192];   // swizzled half of W

    const int tid  = threadIdx.x;
    const int row0 = blockIdx.x * 32;
    const int cg   = tid & 15;
    const int rp   = tid >> 4;
    const int r0   = rp * 2;
    const int c0   = cg * 8;

    for (int q = tid; q < 32 * 32; q += 256) {
        float4 v = *(const float4*)&X[row0 * 128 + q * 4];
        *(float4*)&Xs[(q >> 5) * 132 + (q & 31) * 4] = v;
    }

    float acc[2][8];
    for (int layer = 0; layer < 3; ++layer) {
        const float* __restrict__ W = (layer == 0) ? W0 : (layer == 1) ? W1 : W2;

#pragma unroll
        for (int r = 0; r < 2; ++r)
#pragma unroll
            for (int c = 0; c < 8; ++c) acc[r][c] = 0.0f;

        for (int kh = 0; kh < 2; ++kh) {
            __syncthreads();
#pragma unroll
            for (int it = 0; it < 8; ++it) {
                int q = tid + it * 256;
                int k = q >> 5;
                int j = q & 31;
                float4 v = *(const float4*)&W[(kh * 64 + k) * 128 + j * 4];
                *(float4*)&Ws[k * 192 + (j >> 1) * 12 + (j & 1) * 4] = v;
            }
            __syncthreads();

            for (int k8 = 0; k8 < 8; ++k8) {
                const float* xp0 = &Xs[r0 * 132 + kh * 64 + k8 * 8];
                const float* xp1 = &Xs[(r0 + 1) * 132 + kh * 64 + k8 * 8];
                float4 xa0 = *(const float4*)xp0;
                float4 xb0 = *(const float4*)(xp0 + 4);
                float4 xa1 = *(const float4*)xp1;
                float4 xb1 = *(const float4*)(xp1 + 4);
                float x0a[8] = {xa0.x, xa0.y, xa0.z, xa0.w, xb0.x, xb0.y, xb0.z, xb0.w};
                float x1a[8] = {xa1.x, xa1.y, xa1.z, xa1.w, xb1.x, xb1.y, xb1.z, xb1.w};
#pragma unroll
                for (int j = 0; j < 8; ++j) {
                    const int kk = k8 * 8 + j;
                    const float4 wa = *(const float4*)&Ws[kk * 192 + cg * 12];
                    const float4 wb = *(const float4*)&Ws[kk * 192 + cg * 12 + 4];
                    const float x0 = x0a[j];
                    const float x1 = x1a[j];
                    acc[0][0] += x0 * wa.x; acc[0][1] += x0 * wa.y;
                    acc[0][2] += x0 * wa.z; acc[0][3] += x0 * wa.w;
                    acc[0][4] += x0 * wb.x; acc[0][5] += x0 * wb.y;
                    acc[0][6] += x0 * wb.z; acc[0][7] += x0 * wb.w;
                    acc[1][0] += x1 * wa.x; acc[1][1] += x1 * wa.y;
                    acc[1][2] += x1 * wa.z; acc[1][3] += x1 * wa.w;
                    acc[1][4] += x1 * wb.x; acc[1][5] += x1 * wb.y;
                    acc[1][6] += x1 * wb.z; acc[1][7] += x1 * wb.w;
                }
            }
        }

#pragma unroll
        for (int r = 0; r < 2; ++r)
#pragma unroll
            for (int c = 0; c < 8; ++c) acc[r][c] = fmaxf(acc[r][c], 0.0f);

        __syncthreads();

        if (layer < 2) {
#pragma unroll
            for (int r = 0; r < 2; ++r) {
                *(float4*)&Xs[(r0 + r) * 132 + c0] =
                    make_float4(acc[r][0], acc[r][1], acc[r][2], acc[r][3]);
                *(float4*)&Xs[(r0 + r) * 132 + c0 + 4] =
                    make_float4(acc[r][4], acc[r][5], acc[r][6], acc[r][7]);
            }
        } else {
            const float4 w3a = *(const float4*)&W3[c0];
            const float4 w3b = *(const float4*)&W3[c0 + 4];
            float p0 = acc[0][0] * w3a.x + acc[0][1] * w3a.y + acc[0][2] * w3a.z +
                       acc[0][3] * w3a.w + acc[0][4] * w3b.x + acc[0][5] * w3b.y +
                       acc[0][6] * w3b.z + acc[0][7] * w3b.w;
            float p1 = acc[1][0] * w3a.x + acc[1][1] * w3a.y + acc[1][2] * w3a.z +
                       acc[1][3] * w3a.w + acc[1][4] * w3b.x + acc[1][5] * w3b.y +
                       acc[1][6] * w3b.z + acc[1][7] * w3b.w;
#pragma unroll
            for (int m = 1; m < 16; m <<= 1) {
                p0 += __shfl_xor(p0, m, 64);
                p1 += __shfl_xor(p1, m, 64);
            }
            if (cg == 0) {
                angles[row0 + r0]     = p0;
                angles[row0 + r0 + 1] = p1;
            }
        }
    }
}

// ---------------------------------------------------------------------------
// Merged edge pass: bitset adjacency (dedup by OR) + inline CSR build +
// hop-1 scatter over the RAW edge list (duplicates counted, per reference).
// ---------------------------------------------------------------------------
__global__ void edges_kernel(const int* __restrict__ ei,
                             const float* __restrict__ angles,
                             unsigned int* __restrict__ adj,
                             float* __restrict__ s1,
                             int* __restrict__ cnt_g,
                             int* __restrict__ nbr_g)
{
    int e = blockIdx.x * blockDim.x + threadIdx.x;
    if (e < NE) {
        int r = ei[e];
        int c = ei[NE + e];
        unsigned int bit = 1u << (c & 31);
        unsigned int old = atomicOr(&adj[r * WPR + (c >> 5)], bit);
        if (!(old & bit)) {
            int p = atomicAdd(&cnt_g[r], 1);
            if (p < MAXD) nbr_g[r * MAXD + p] = c;
        }
        atomicAdd(&s1[r], F1 * angles[c]);
    }
}

// ---------------------------------------------------------------------------
// P2 row i = 2-hop union via CSR, built in a per-wave LDS bitmap.
// NEW: emit P2 row as a packed u16 id-list (wave prefix-scan for offsets,
// padded to even length with a duplicated id so p3 can read u32 pairs).
// Sparse dot vs e1 (= angles+s1) unchanged -> bit-identical s2/e2.
// One wave per row, 4 rows/block.
// ---------------------------------------------------------------------------
__global__ __launch_bounds__(256) void p2_kernel(
    const int* __restrict__ cnt_g, const int* __restrict__ nbr_g,
    unsigned short* __restrict__ P2L, int* __restrict__ cnt2_g,
    const float* __restrict__ angles, const float* __restrict__ s1,
    float* __restrict__ s2, float* __restrict__ e2)
{
    __shared__ unsigned int bm[4][WPR];  // 4 KB: per-wave bitmap
    __shared__ int nbr[4][MAXD];
    __shared__ int nc[4][MAXD];

    const int wv = threadIdx.x >> 6;
    const int l  = threadIdx.x & 63;
    const int i  = blockIdx.x * 4 + wv;

#pragma unroll
    for (int s = 0; s < 4; ++s) bm[wv][s * 64 + l] = 0u;

    const int n = min(cnt_g[i], MAXD);
    if (l < n) {
        int m = nbr_g[i * MAXD + l];
        nbr[wv][l] = m;
        nc[wv][l]  = min(cnt_g[m], MAXD);
    }
    __syncthreads();

    for (int q = 0; q < n; ++q) {
        int m  = nbr[wv][q];
        int c2 = nc[wv][q];
        if (l < c2) {
            int id = nbr_g[m * MAXD + l];
            atomicOr(&bm[wv][id >> 5], 1u << (id & 31));
        }
    }
    __syncthreads();

    unsigned int w[4];
#pragma unroll
    for (int s = 0; s < 4; ++s) w[s] = bm[wv][s * 64 + l];

    // ---- emit u16 id list via wave prefix scan ----
    int cnt_lane = __popc(w[0]) + __popc(w[1]) + __popc(w[2]) + __popc(w[3]);
    int incl = cnt_lane;
#pragma unroll
    for (int d = 1; d < 64; d <<= 1) {
        int v = __shfl_up(incl, d, 64);
        if (l >= d) incl += v;
    }
    const int total = __shfl(incl, 63, 64);

    unsigned short* dst = P2L + (size_t)i * MAXP2;
    int p = incl - cnt_lane;     // exclusive offset
    int last = 0;
#pragma unroll
    for (int s = 0; s < 4; ++s) {
        unsigned int ww = w[s];
        const int base = (s * 64 + l) * 32;
        while (ww) {
            int b = __ffs(ww) - 1;
            ww &= ww - 1;
            last = base + b;
            if (p < MAXP2) dst[p] = (unsigned short)last;
            ++p;
        }
    }
    // pad to even with a duplicate of the final id (harmless for OR)
    if ((total & 1) && (incl == total) && cnt_lane > 0 && total < MAXP2)
        dst[total] = (unsigned short)last;
    if (l == 0) cnt2_g[i] = min(total + (total & 1), MAXP2);

    // ---- sparse dot (identical order to previous rounds) ----
    float local = 0.0f;
#pragma unroll
    for (int s = 0; s < 4; ++s) {
        unsigned int ww = w[s];
        const int base = (s * 64 + l) * 32;
        while (ww) {
            int b = __ffs(ww) - 1;
            ww &= ww - 1;
            local += angles[base + b] + s1[base + b];
        }
    }
#pragma unroll
    for (int m = 1; m < 64; m <<= 1) local += __shfl_xor(local, m, 64);
    if (l == 0) {
        float e1i = angles[i] + s1[i];
        float s2v = s1[i] + F2 * local;
        s2[i] = s2v;
        e2[i] = e1i + s2v;
    }
}

// ---------------------------------------------------------------------------
// P3 row i (never materialized) = union of P2 id-lists of i's neighbors,
// rebuilt in a per-wave LDS bitmap (u32-pair list reads, ~63 MB total vs
// 134 MB for bitmap rows). Dense dot reads the mask nibble from LDS.
// out[i] = e2[i] + s2[i] + F3 * (P3[i] . e2)
// ---------------------------------------------------------------------------
__global__ __launch_bounds__(256) void p3_kernel(
    const unsigned short* __restrict__ P2L, const int* __restrict__ cnt2_g,
    const int* __restrict__ cnt_g, const int* __restrict__ nbr_g,
    const float* __restrict__ e2, const float* __restrict__ s2,
    float* __restrict__ out)
{
    __shared__ unsigned int bm[4][WPR];  // per-wave union bitmap
    __shared__ int nbr[4][MAXD];
    __shared__ int nc2[4][MAXD];

    const int wv = threadIdx.x >> 6;
    const int l  = threadIdx.x & 63;
    const int i  = blockIdx.x * 4 + wv;

#pragma unroll
    for (int s = 0; s < 4; ++s) bm[wv][s * 64 + l] = 0u;

    const int n = min(cnt_g[i], MAXD);
    if (l < n) {
        int m = nbr_g[i * MAXD + l];
        nbr[wv][l]  = m;
        nc2[wv][l]  = cnt2_g[m];
    }
    __syncthreads();

    for (int q = 0; q < n; ++q) {
        int m     = nbr[wv][q];
        int npair = nc2[wv][q] >> 1;  // even by construction
        const unsigned int* lp = (const unsigned int*)(P2L + (size_t)m * MAXP2);
        for (int t = l; t < npair; t += 64) {
            unsigned int pr  = lp[t];
            int id0 = pr & 0xFFFF;
            int id1 = pr >> 16;
            atomicOr(&bm[wv][id0 >> 5], 1u << (id0 & 31));
            atomicOr(&bm[wv][id1 >> 5], 1u << (id1 & 31));
        }
    }
    __syncthreads();

    // dense dot: 32 chunks; lane l reads float4 e2[c*256+4l] (coalesced);
    // mask nibble from LDS bm (8 words/chunk, 8-lane broadcast each: no conflict)
    float local = 0.0f;
#pragma unroll
    for (int c = 0; c < 32; ++c) {
        unsigned int wd  = bm[wv][c * 8 + (l >> 3)];
        unsigned int nib = wd >> ((l & 7) * 4);
        float4 v = *(const float4*)&e2[c * 256 + l * 4];
        local += (nib & 1u) ? v.x : 0.0f;
        local += (nib & 2u) ? v.y : 0.0f;
        local += (nib & 4u) ? v.z : 0.0f;
        local += (nib & 8u) ? v.w : 0.0f;
    }
#pragma unroll
    for (int m = 1; m < 64; m <<= 1) local += __shfl_xor(local, m, 64);
    if (l == 0)
        out[i] = e2[i] + s2[i] + F3 * local;
}

// ---------------------------------------------------------------------------
// Launch
// ---------------------------------------------------------------------------
extern "C" void kernel_launch(void* const* d_in, const int* in_sizes, int n_in,
                              void* d_out, int out_size, void* d_ws, size_t ws_size,
                              hipStream_t stream)
{
    const float* coeffs = (const float*)d_in[0];
    const float* W0     = (const float*)d_in[1];
    const float* W1     = (const float*)d_in[2];
    const float* W2     = (const float*)d_in[3];
    const float* W3     = (const float*)d_in[4];
    const int*   ei     = (const int*)  d_in[5];
    float* out = (float*)d_out;

    char* ws = (char*)d_ws;
    // workspace layout (bytes)
    float*          angles = (float*)(ws + 0 * 32768);
    float*          s2     = (float*)(ws + 1 * 32768);
    float*          e2     = (float*)(ws + 2 * 32768);
    int*            cnt2_g = (int*)  (ws + 3 * 32768);
    int*            nbr_g  = (int*)  (ws + (1u  << 20));        // 2 MB
    unsigned int*   adj    = (unsigned int*)(ws + (4u  << 20)); // 8 MB
    float*          s1     = (float*)(ws + (12u << 20));        // 32 KB, after adj
    int*            cnt_g  = (int*)  (ws + (12u << 20) + 32768);// 32 KB, after s1
    unsigned short* P2L    = (unsigned short*)(ws + (13u << 20)); // 16 MB

    // one memset covers adj (8 MB) + s1 + cnt_g (contiguous)
    hipMemsetAsync(adj, 0,
                   ((size_t)N * WPR) * sizeof(unsigned int) + 2 * N * sizeof(float),
                   stream);

    // MLP: single fused kernel
    mlp_kernel<<<N / 32, 256, 0, stream>>>(coeffs, W0, W1, W2, W3, angles);

    // graph side
    edges_kernel<<<NE / 256, 256, 0, stream>>>(ei, angles, adj, s1, cnt_g, nbr_g);
    p2_kernel<<<N / 4, 256, 0, stream>>>(cnt_g, nbr_g, P2L, cnt2_g, angles, s1, s2, e2);
    p3_kernel<<<N / 4, 256, 0, stream>>>(P2L, cnt2_g, cnt_g, nbr_g, e2, s2, out);
}

// Round 7
// 135.448 us; speedup vs baseline: 1.1912x; 1.1912x over previous
//
#include <hip/hip_runtime.h>

// Problem constants (match reference)
constexpr int N    = 8192;     // nodes
constexpr int NE   = 131072;   // edges
constexpr int WPR  = N / 32;   // 256 u32 words per bitset row
constexpr int MAXD = 64;       // max distinct out-degree (actual max ~45)

// f(k) = exp(-ALPHA*k), ALPHA = 2
#define F1 0.13533528323661270f   // e^-2
#define F2 0.018315638888734179f  // e^-4
#define F3 0.0024787521766663585f // e^-6

using bf16x8 = __attribute__((ext_vector_type(8))) short;
using f32x4  = __attribute__((ext_vector_type(4))) float;

__device__ __forceinline__ unsigned short f2bf(float f) {
    unsigned int u = __float_as_uint(f);
    u = (u + 0x7FFFu + ((u >> 16) & 1u)) >> 16;   // round-to-nearest-even
    return (unsigned short)u;
}

// ---------------------------------------------------------------------------
// One-off: convert W0/W1/W2 (fp32 [k][n]) -> Wt_g (bf16 [layer][n][k]).
// Coalesced reads (consecutive n), strided b16 writes (L2-resident, 96 KB).
// ---------------------------------------------------------------------------
__global__ void wtprep(const float* __restrict__ W0, const float* __restrict__ W1,
                       const float* __restrict__ W2, unsigned short* __restrict__ Wt_g)
{
    int idx = blockIdx.x * 256 + threadIdx.x;      // 0 .. 49151
    int l   = idx >> 14;
    int r   = idx & 16383;
    int k   = r >> 7;
    int n   = r & 127;
    const float* W = (l == 0) ? W0 : (l == 1) ? W1 : W2;
    Wt_g[l * 16384 + n * 128 + k] = f2bf(W[k * 128 + n]);
}

// ---------------------------------------------------------------------------
// Fused MLP on matrix cores: angles = relu(relu(relu(X@W0)@W1)@W2) @ W3.
// Block = 32 rows, 256 threads = 4 waves: wave w -> m-tile (w&1), n-half (w>>1).
// Per wave per layer: 4 kc x (1 A-ds_read_b128 + 4x[B-ds_read_b128 + mfma]).
// LDS: Xb 32x136 bf16 (8.5 KB) + Wt 128x136 bf16 (34 KB); stride 136 keeps
// 16-B alignment (272 B/row) and spreads banks (68 words, odd multiple of 4).
// C/D layout (m89-verified): col = lane&15, row = (lane>>4)*4 + reg.
// A: [m=lane&15][k=(lane>>4)*8+j];  B: [k=(lane>>4)*8+j][n=lane&15].
// ---------------------------------------------------------------------------
__global__ __launch_bounds__(256) void mlp_kernel(
    const float* __restrict__ X, const unsigned short* __restrict__ Wt_g,
    const float* __restrict__ W3, float* __restrict__ angles)
{
    __shared__ unsigned short Xb[32 * 136];
    __shared__ unsigned short Wt[128 * 136];
    __shared__ float part[2][32];

    const int tid  = threadIdx.x;
    const int row0 = blockIdx.x * 32;
    const int w  = tid >> 6, l = tid & 63;
    const int mt = w & 1, nh = w >> 1;
    const int lm = l & 15, lq = l >> 4;

    // stage X (fp32 -> bf16), coalesced float4 reads, b64 stores
    for (int q = tid; q < 32 * 32; q += 256) {
        float4 v = *(const float4*)&X[row0 * 128 + q * 4];
        ushort4 b;
        b.x = f2bf(v.x); b.y = f2bf(v.y); b.z = f2bf(v.z); b.w = f2bf(v.w);
        *(ushort4*)&Xb[(q >> 5) * 136 + (q & 31) * 4] = b;
    }

    for (int layer = 0; layer < 3; ++layer) {
        // stage W^T bf16 (32 KB) from global, coalesced 16-B chunks
        const unsigned short* Wg = Wt_g + layer * 16384;
        for (int q = tid; q < 2048; q += 256) {
            int n = q >> 4, ck = (q & 15) * 8;
            uint4 v = *(const uint4*)&Wg[n * 128 + ck];
            *(uint4*)&Wt[n * 136 + ck] = v;
        }
        __syncthreads();   // Wt staged; Xb (stage or prev writeback) visible

        f32x4 acc[4];
#pragma unroll
        for (int t = 0; t < 4; ++t) acc[t] = (f32x4){0.f, 0.f, 0.f, 0.f};

#pragma unroll
        for (int kc = 0; kc < 4; ++kc) {
            bf16x8 a = *(const bf16x8*)&Xb[(mt * 16 + lm) * 136 + kc * 32 + lq * 8];
#pragma unroll
            for (int t = 0; t < 4; ++t) {
                bf16x8 b = *(const bf16x8*)
                    &Wt[(nh * 64 + t * 16 + lm) * 136 + kc * 32 + lq * 8];
                acc[t] = __builtin_amdgcn_mfma_f32_16x16x32_bf16(a, b, acc[t], 0, 0, 0);
            }
        }

        // relu
#pragma unroll
        for (int t = 0; t < 4; ++t)
#pragma unroll
            for (int r = 0; r < 4; ++r) acc[t][r] = fmaxf(acc[t][r], 0.0f);

        __syncthreads();   // all waves done reading Xb/Wt before overwrite

        if (layer < 2) {
            // writeback h -> Xb (bf16), C-layout scatter (b16 stores)
#pragma unroll
            for (int t = 0; t < 4; ++t)
#pragma unroll
                for (int r = 0; r < 4; ++r)
                    Xb[(mt * 16 + lq * 4 + r) * 136 + nh * 64 + t * 16 + lm] =
                        f2bf(acc[t][r]);
        } else {
            // fused W3 dot: partial over this wave's 64 cols, fp32
            float p[4] = {0.f, 0.f, 0.f, 0.f};
#pragma unroll
            for (int t = 0; t < 4; ++t) {
                float w3v = W3[nh * 64 + t * 16 + lm];
#pragma unroll
                for (int r = 0; r < 4; ++r) p[r] += acc[t][r] * w3v;
            }
#pragma unroll
            for (int r = 0; r < 4; ++r) {
                p[r] += __shfl_xor(p[r], 1, 64);
                p[r] += __shfl_xor(p[r], 2, 64);
                p[r] += __shfl_xor(p[r], 4, 64);
                p[r] += __shfl_xor(p[r], 8, 64);
            }
            if (lm == 0)
#pragma unroll
                for (int r = 0; r < 4; ++r)
                    part[nh][mt * 16 + lq * 4 + r] = p[r];
            __syncthreads();
            if (tid < 32) angles[row0 + tid] = part[0][tid] + part[1][tid];
        }
    }
}

// ---------------------------------------------------------------------------
// Merged edge pass: bitset adjacency (dedup by OR) + inline CSR build +
// hop-1 scatter over the RAW edge list (duplicates counted, per reference).
// ---------------------------------------------------------------------------
__global__ void edges_kernel(const int* __restrict__ ei,
                             const float* __restrict__ angles,
                             unsigned int* __restrict__ adj,
                             float* __restrict__ s1,
                             int* __restrict__ cnt_g,
                             int* __restrict__ nbr_g)
{
    int e = blockIdx.x * blockDim.x + threadIdx.x;
    if (e < NE) {
        int r = ei[e];
        int c = ei[NE + e];
        unsigned int bit = 1u << (c & 31);
        unsigned int old = atomicOr(&adj[r * WPR + (c >> 5)], bit);
        if (!(old & bit)) {
            int p = atomicAdd(&cnt_g[r], 1);
            if (p < MAXD) nbr_g[r * MAXD + p] = c;
        }
        atomicAdd(&s1[r], F1 * angles[c]);
    }
}

// ---------------------------------------------------------------------------
// P2 row i = 2-hop union via CSR, built in a per-wave LDS bitmap (R5 form).
// One wave per row, 4 rows/block. Writes P2 bitmap (stride-64 lane layout) +
// sparse dot vs e1 (= angles+s1, never materialized). Epilogue: s2/e2.
// ---------------------------------------------------------------------------
__global__ __launch_bounds__(256) void p2_kernel(
    const int* __restrict__ cnt_g, const int* __restrict__ nbr_g,
    unsigned int* __restrict__ P2,
    const float* __restrict__ angles, const float* __restrict__ s1,
    float* __restrict__ s2, float* __restrict__ e2)
{
    __shared__ unsigned int bm[4][WPR];  // 4 KB: per-wave bitmap
    __shared__ int nbr[4][MAXD];
    __shared__ int nc[4][MAXD];

    const int wv = threadIdx.x >> 6;
    const int l  = threadIdx.x & 63;
    const int i  = blockIdx.x * 4 + wv;

#pragma unroll
    for (int s = 0; s < 4; ++s) bm[wv][s * 64 + l] = 0u;

    const int n = min(cnt_g[i], MAXD);
    if (l < n) {
        int m = nbr_g[i * MAXD + l];
        nbr[wv][l] = m;
        nc[wv][l]  = min(cnt_g[m], MAXD);
    }
    __syncthreads();

    for (int q = 0; q < n; ++q) {
        int m  = nbr[wv][q];
        int c2 = nc[wv][q];
        if (l < c2) {
            int id = nbr_g[m * MAXD + l];
            atomicOr(&bm[wv][id >> 5], 1u << (id & 31));
        }
    }
    __syncthreads();

    unsigned int w[4];
#pragma unroll
    for (int s = 0; s < 4; ++s) {
        w[s] = bm[wv][s * 64 + l];
        P2[(size_t)i * WPR + s * 64 + l] = w[s];
    }

    // sparse dot: ~4 set bits/lane -> ffs iterate, gather e1 on the fly
    float local = 0.0f;
#pragma unroll
    for (int s = 0; s < 4; ++s) {
        unsigned int ww = w[s];
        const int base = (s * 64 + l) * 32;
        while (ww) {
            int b = __ffs(ww) - 1;
            ww &= ww - 1;
            local += angles[base + b] + s1[base + b];
        }
    }
#pragma unroll
    for (int m = 1; m < 64; m <<= 1) local += __shfl_xor(local, m, 64);
    if (l == 0) {
        float e1i = angles[i] + s1[i];
        float s2v = s1[i] + F2 * local;
        s2[i] = s2v;
        e2[i] = e1i + s2v;
    }
}

// ---------------------------------------------------------------------------
// P3 row i (never materialized) = OR of P2 bitmap rows of i's neighbors.
// out[i] = e2[i] + s2[i] + F3 * (P3[i] . e2)   (R4/R5 form)
// ---------------------------------------------------------------------------
__global__ __launch_bounds__(256) void p3_kernel(
    const unsigned int* __restrict__ P2,
    const int* __restrict__ cnt_g, const int* __restrict__ nbr_g,
    const float* __restrict__ e2, const float* __restrict__ s2,
    float* __restrict__ out)
{
    __shared__ int nbr[4][MAXD];

    const int wv = threadIdx.x >> 6;
    const int l  = threadIdx.x & 63;
    const int i  = blockIdx.x * 4 + wv;

    const int n = min(cnt_g[i], MAXD);
    if (l < n) nbr[wv][l] = nbr_g[i * MAXD + l];
    __syncthreads();

    unsigned int w[4] = {0u, 0u, 0u, 0u};
    for (int q = 0; q < n; ++q) {
        const unsigned int* rowp = P2 + (size_t)nbr[wv][q] * WPR + l;
#pragma unroll
        for (int s = 0; s < 4; ++s) w[s] |= rowp[s * 64];
    }

    float local = 0.0f;
#pragma unroll
    for (int c = 0; c < 32; ++c) {
        unsigned int wd  = __shfl(w[c >> 3], ((c & 7) << 3) | (l >> 3), 64);
        unsigned int nib = wd >> ((l & 7) * 4);
        float4 v = *(const float4*)&e2[c * 256 + l * 4];
        local += (nib & 1u) ? v.x : 0.0f;
        local += (nib & 2u) ? v.y : 0.0f;
        local += (nib & 4u) ? v.z : 0.0f;
        local += (nib & 8u) ? v.w : 0.0f;
    }
#pragma unroll
    for (int m = 1; m < 64; m <<= 1) local += __shfl_xor(local, m, 64);
    if (l == 0)
        out[i] = e2[i] + s2[i] + F3 * local;
}

// ---------------------------------------------------------------------------
// Launch
// ---------------------------------------------------------------------------
extern "C" void kernel_launch(void* const* d_in, const int* in_sizes, int n_in,
                              void* d_out, int out_size, void* d_ws, size_t ws_size,
                              hipStream_t stream)
{
    const float* coeffs = (const float*)d_in[0];
    const float* W0     = (const float*)d_in[1];
    const float* W1     = (const float*)d_in[2];
    const float* W2     = (const float*)d_in[3];
    const float* W3     = (const float*)d_in[4];
    const int*   ei     = (const int*)  d_in[5];
    float* out = (float*)d_out;

    char* ws = (char*)d_ws;
    // workspace layout (bytes)
    float*          angles = (float*)(ws + 0 * 32768);
    float*          s2     = (float*)(ws + 1 * 32768);
    float*          e2     = (float*)(ws + 2 * 32768);
    unsigned short* Wt_g   = (unsigned short*)(ws + 4 * 32768); // 96 KB
    int*            nbr_g  = (int*)  (ws + (1u  << 20));        // 2 MB
    unsigned int*   adj    = (unsigned int*)(ws + (4u  << 20)); // 8 MB
    float*          s1     = (float*)(ws + (12u << 20));        // 32 KB, after adj
    int*            cnt_g  = (int*)  (ws + (12u << 20) + 32768);// 32 KB, after s1
    unsigned int*   P2     = (unsigned int*)(ws + (13u << 20)); // 8 MB

    // one memset covers adj (8 MB) + s1 + cnt_g (contiguous)
    hipMemsetAsync(adj, 0,
                   ((size_t)N * WPR) * sizeof(unsigned int) + 2 * N * sizeof(float),
                   stream);

    // W^T bf16 prep (one-off), then MFMA MLP
    wtprep<<<192, 256, 0, stream>>>(W0, W1, W2, Wt_g);
    mlp_kernel<<<N / 32, 256, 0, stream>>>(coeffs, Wt_g, W3, angles);

    // graph side
    edges_kernel<<<NE / 256, 256, 0, stream>>>(ei, angles, adj, s1, cnt_g, nbr_g);
    p2_kernel<<<N / 4, 256, 0, stream>>>(cnt_g, nbr_g, P2, angles, s1, s2, e2);
    p3_kernel<<<N / 4, 256, 0, stream>>>(P2, cnt_g, nbr_g, e2, s2, out);
}

// Round 9
// 133.749 us; speedup vs baseline: 1.2064x; 1.0127x over previous
//
#include <hip/hip_runtime.h>

// Problem constants (match reference)
constexpr int N    = 8192;     // nodes
constexpr int NE   = 131072;   // edges
constexpr int WPR  = N / 32;   // 256 u32 words per bitset row
constexpr int MAXD = 64;       // max distinct out-degree (actual max ~45)

// f(k) = exp(-ALPHA*k), ALPHA = 2
#define F1 0.13533528323661270f   // e^-2
#define F2 0.018315638888734179f  // e^-4
#define F3 0.0024787521766663585f // e^-6

using bf16x8 = __attribute__((ext_vector_type(8))) short;
using f32x4  = __attribute__((ext_vector_type(4))) float;

__device__ __forceinline__ unsigned short f2bf(float f) {
    unsigned int u = __float_as_uint(f);
    u = (u + 0x7FFFu + ((u >> 16) & 1u)) >> 16;   // round-to-nearest-even
    return (unsigned short)u;
}

// ---------------------------------------------------------------------------
// Prelude (one regular dispatch): zero adj (8 MB) + s1 + cnt (64 KB) with
// uint4 stores, AND convert W0/W1/W2 (fp32 [k][n]) -> Wt_g (bf16 [layer][n][k]).
// ---------------------------------------------------------------------------
__global__ __launch_bounds__(256) void prelude(
    const float* __restrict__ W0, const float* __restrict__ W1,
    const float* __restrict__ W2, unsigned short* __restrict__ Wt_g,
    uint4* __restrict__ zbase)
{
    int gt = blockIdx.x * 256 + threadIdx.x;      // 0 .. 131071
    const uint4 z = {0u, 0u, 0u, 0u};
    // 8 MB + 64 KB = 528384 uint4
    for (int q = gt; q < 528384; q += 131072) zbase[q] = z;

    if (gt < 49152) {
        int l = gt >> 14;
        int r = gt & 16383;
        int k = r >> 7;
        int n = r & 127;
        const float* W = (l == 0) ? W0 : (l == 1) ? W1 : W2;
        Wt_g[l * 16384 + n * 128 + k] = f2bf(W[k * 128 + n]);
    }
}

// ---------------------------------------------------------------------------
// Fused MLP on matrix cores (R7 form, verified at absmax 0.25).
// C/D layout (m89-verified): col = lane&15, row = (lane>>4)*4 + reg.
// A: [m=lane&15][k=(lane>>4)*8+j];  B: [k=(lane>>4)*8+j][n=lane&15].
// ---------------------------------------------------------------------------
__global__ __launch_bounds__(256) void mlp_kernel(
    const float* __restrict__ X, const unsigned short* __restrict__ Wt_g,
    const float* __restrict__ W3, float* __restrict__ angles)
{
    __shared__ unsigned short Xb[32 * 136];
    __shared__ unsigned short Wt[128 * 136];
    __shared__ float part[2][32];

    const int tid  = threadIdx.x;
    const int row0 = blockIdx.x * 32;
    const int w  = tid >> 6, l = tid & 63;
    const int mt = w & 1, nh = w >> 1;
    const int lm = l & 15, lq = l >> 4;

    // stage X (fp32 -> bf16), coalesced float4 reads, b64 stores
    for (int q = tid; q < 32 * 32; q += 256) {
        float4 v = *(const float4*)&X[row0 * 128 + q * 4];
        ushort4 b;
        b.x = f2bf(v.x); b.y = f2bf(v.y); b.z = f2bf(v.z); b.w = f2bf(v.w);
        *(ushort4*)&Xb[(q >> 5) * 136 + (q & 31) * 4] = b;
    }

    for (int layer = 0; layer < 3; ++layer) {
        // stage W^T bf16 (32 KB) from global, coalesced 16-B chunks
        const unsigned short* Wg = Wt_g + layer * 16384;
        for (int q = tid; q < 2048; q += 256) {
            int n = q >> 4, ck = (q & 15) * 8;
            uint4 v = *(const uint4*)&Wg[n * 128 + ck];
            *(uint4*)&Wt[n * 136 + ck] = v;
        }
        __syncthreads();   // Wt staged; Xb (stage or prev writeback) visible

        f32x4 acc[4];
#pragma unroll
        for (int t = 0; t < 4; ++t) acc[t] = (f32x4){0.f, 0.f, 0.f, 0.f};

#pragma unroll
        for (int kc = 0; kc < 4; ++kc) {
            bf16x8 a = *(const bf16x8*)&Xb[(mt * 16 + lm) * 136 + kc * 32 + lq * 8];
#pragma unroll
            for (int t = 0; t < 4; ++t) {
                bf16x8 b = *(const bf16x8*)
                    &Wt[(nh * 64 + t * 16 + lm) * 136 + kc * 32 + lq * 8];
                acc[t] = __builtin_amdgcn_mfma_f32_16x16x32_bf16(a, b, acc[t], 0, 0, 0);
            }
        }

        // relu
#pragma unroll
        for (int t = 0; t < 4; ++t)
#pragma unroll
            for (int r = 0; r < 4; ++r) acc[t][r] = fmaxf(acc[t][r], 0.0f);

        __syncthreads();   // all waves done reading Xb/Wt before overwrite

        if (layer < 2) {
            // writeback h -> Xb (bf16), C-layout scatter (b16 stores)
#pragma unroll
            for (int t = 0; t < 4; ++t)
#pragma unroll
                for (int r = 0; r < 4; ++r)
                    Xb[(mt * 16 + lq * 4 + r) * 136 + nh * 64 + t * 16 + lm] =
                        f2bf(acc[t][r]);
        } else {
            // fused W3 dot: partial over this wave's 64 cols, fp32
            float p[4] = {0.f, 0.f, 0.f, 0.f};
#pragma unroll
            for (int t = 0; t < 4; ++t) {
                float w3v = W3[nh * 64 + t * 16 + lm];
#pragma unroll
                for (int r = 0; r < 4; ++r) p[r] += acc[t][r] * w3v;
            }
#pragma unroll
            for (int r = 0; r < 4; ++r) {
                p[r] += __shfl_xor(p[r], 1, 64);
                p[r] += __shfl_xor(p[r], 2, 64);
                p[r] += __shfl_xor(p[r], 4, 64);
                p[r] += __shfl_xor(p[r], 8, 64);
            }
            if (lm == 0)
#pragma unroll
                for (int r = 0; r < 4; ++r)
                    part[nh][mt * 16 + lq * 4 + r] = p[r];
            __syncthreads();
            if (tid < 32) angles[row0 + tid] = part[0][tid] + part[1][tid];
        }
    }
}

// ---------------------------------------------------------------------------
// Merged edge pass: bitset adjacency (dedup by OR) + inline CSR build +
// hop-1 scatter over the RAW edge list (duplicates counted, per reference).
// ---------------------------------------------------------------------------
__global__ void edges_kernel(const int* __restrict__ ei,
                             const float* __restrict__ angles,
                             unsigned int* __restrict__ adj,
                             float* __restrict__ s1,
                             int* __restrict__ cnt_g,
                             int* __restrict__ nbr_g)
{
    int e = blockIdx.x * blockDim.x + threadIdx.x;
    if (e < NE) {
        int r = ei[e];
        int c = ei[NE + e];
        unsigned int bit = 1u << (c & 31);
        unsigned int old = atomicOr(&adj[r * WPR + (c >> 5)], bit);
        if (!(old & bit)) {
            int p = atomicAdd(&cnt_g[r], 1);
            if (p < MAXD) nbr_g[r * MAXD + p] = c;
        }
        atomicAdd(&s1[r], F1 * angles[c]);
    }
}

// ---------------------------------------------------------------------------
// P2 row i = 2-hop union via CSR, built in a per-wave LDS bitmap.
// One wave per row, 4 rows/block. Writes P2 bitmap (stride-64 lane layout) +
// sparse dot vs e1 (= angles+s1, never materialized). Epilogue: s2/e2.
// ---------------------------------------------------------------------------
__global__ __launch_bounds__(256) void p2_kernel(
    const int* __restrict__ cnt_g, const int* __restrict__ nbr_g,
    unsigned int* __restrict__ P2,
    const float* __restrict__ angles, const float* __restrict__ s1,
    float* __restrict__ s2, float* __restrict__ e2)
{
    __shared__ unsigned int bm[4][WPR];  // 4 KB: per-wave bitmap
    __shared__ int nbr[4][MAXD];
    __shared__ int nc[4][MAXD];

    const int wv = threadIdx.x >> 6;
    const int l  = threadIdx.x & 63;
    const int i  = blockIdx.x * 4 + wv;

#pragma unroll
    for (int s = 0; s < 4; ++s) bm[wv][s * 64 + l] = 0u;

    const int n = min(cnt_g[i], MAXD);
    if (l < n) {
        int m = nbr_g[i * MAXD + l];
        nbr[wv][l] = m;
        nc[wv][l]  = min(cnt_g[m], MAXD);
    }
    __syncthreads();

    for (int q = 0; q < n; ++q) {
        int m  = nbr[wv][q];
        int c2 = nc[wv][q];
        if (l < c2) {
            int id = nbr_g[m * MAXD + l];
            atomicOr(&bm[wv][id >> 5], 1u << (id & 31));
        }
    }
    __syncthreads();

    unsigned int w[4];
#pragma unroll
    for (int s = 0; s < 4; ++s) {
        w[s] = bm[wv][s * 64 + l];
        P2[(size_t)i * WPR + s * 64 + l] = w[s];
    }

    // sparse dot: ~4 set bits/lane -> ffs iterate, gather e1 on the fly
    float local = 0.0f;
#pragma unroll
    for (int s = 0; s < 4; ++s) {
        unsigned int ww = w[s];
        const int base = (s * 64 + l) * 32;
        while (ww) {
            int b = __ffs(ww) - 1;
            ww &= ww - 1;
            local += angles[base + b] + s1[base + b];
        }
    }
#pragma unroll
    for (int m = 1; m < 64; m <<= 1) local += __shfl_xor(local, m, 64);
    if (l == 0) {
        float e1i = angles[i] + s1[i];
        float s2v = s1[i] + F2 * local;
        s2[i] = s2v;
        e2[i] = e1i + s2v;
    }
}

// ---------------------------------------------------------------------------
// P3 row i (never materialized) = OR of P2 bitmap rows of i's neighbors.
// out[i] = e2[i] + s2[i] + F3 * (P3[i] . e2)
// One wave per row. Dense dot: 32 chunks; lane l reads float4 e2[c*256+4l]
// (coalesced 1KB/instr); mask nibble fetched from the owning lane with one
// __shfl per chunk (register slot c>>3 is uniform).
// ---------------------------------------------------------------------------
__global__ __launch_bounds__(256) void p3_kernel(
    const unsigned int* __restrict__ P2,
    const int* __restrict__ cnt_g, const int* __restrict__ nbr_g,
    const float* __restrict__ e2, const float* __restrict__ s2,
    float* __restrict__ out)
{
    __shared__ int nbr[4][MAXD];

    const int wv = threadIdx.x >> 6;
    const int l  = threadIdx.x & 63;
    const int i  = blockIdx.x * 4 + wv;

    const int n = min(cnt_g[i], MAXD);
    if (l < n) nbr[wv][l] = nbr_g[i * MAXD + l];
    __syncthreads();

    unsigned int w[4] = {0u, 0u, 0u, 0u};
    for (int q = 0; q < n; ++q) {
        const unsigned int* rowp = P2 + (size_t)nbr[wv][q] * WPR + l;
#pragma unroll
        for (int s = 0; s < 4; ++s) w[s] |= rowp[s * 64];
    }

    float local = 0.0f;
#pragma unroll
    for (int c = 0; c < 32; ++c) {
        unsigned int wd  = __shfl(w[c >> 3], ((c & 7) << 3) | (l >> 3), 64);
        unsigned int nib = wd >> ((l & 7) * 4);
        float4 v = *(const float4*)&e2[c * 256 + l * 4];
        local += (nib & 1u) ? v.x : 0.0f;
        local += (nib & 2u) ? v.y : 0.0f;
        local += (nib & 4u) ? v.z : 0.0f;
        local += (nib & 8u) ? v.w : 0.0f;
    }
#pragma unroll
    for (int m = 1; m < 64; m <<= 1) local += __shfl_xor(local, m, 64);
    if (l == 0)
        out[i] = e2[i] + s2[i] + F3 * local;
}

// ---------------------------------------------------------------------------
// Launch (5 dispatches, all regular — cooperative launch fails under the
// harness's graph capture, see R8 post-mortem)
// ---------------------------------------------------------------------------
extern "C" void kernel_launch(void* const* d_in, const int* in_sizes, int n_in,
                              void* d_out, int out_size, void* d_ws, size_t ws_size,
                              hipStream_t stream)
{
    const float* coeffs = (const float*)d_in[0];
    const float* W0     = (const float*)d_in[1];
    const float* W1     = (const float*)d_in[2];
    const float* W2     = (const float*)d_in[3];
    const float* W3     = (const float*)d_in[4];
    const int*   ei     = (const int*)  d_in[5];
    float* out = (float*)d_out;

    char* ws = (char*)d_ws;
    // workspace layout (bytes)
    float*          angles = (float*)(ws + 0 * 32768);            // 32 KB
    float*          s2     = (float*)(ws + 1 * 32768);            // 32 KB
    float*          e2     = (float*)(ws + 2 * 32768);            // 32 KB
    unsigned short* Wt_g   = (unsigned short*)(ws + 4 * 32768);   // 96 KB
    int*            nbr_g  = (int*)  (ws + (1u  << 20));          // 2 MB
    unsigned int*   adj    = (unsigned int*)(ws + (4u  << 20));   // 8 MB
    float*          s1     = (float*)(ws + (12u << 20));          // 32 KB
    int*            cnt_g  = (int*)  (ws + (12u << 20) + 32768);  // 32 KB
    unsigned int*   P2     = (unsigned int*)(ws + (13u << 20));   // 8 MB

    // 1) zero adj+s1+cnt AND convert W -> bf16 W^T (one dispatch)
    prelude<<<512, 256, 0, stream>>>(W0, W1, W2, Wt_g, (uint4*)adj);

    // 2) MFMA MLP
    mlp_kernel<<<N / 32, 256, 0, stream>>>(coeffs, Wt_g, W3, angles);

    // 3-5) graph side
    edges_kernel<<<NE / 256, 256, 0, stream>>>(ei, angles, adj, s1, cnt_g, nbr_g);
    p2_kernel<<<N / 4, 256, 0, stream>>>(cnt_g, nbr_g, P2, angles, s1, s2, e2);
    p3_kernel<<<N / 4, 256, 0, stream>>>(P2, cnt_g, nbr_g, e2, s2, out);
}

// Round 10
// 126.813 us; speedup vs baseline: 1.2724x; 1.0547x over previous
//
#include <hip/hip_runtime.h>

// Problem constants (match reference)
constexpr int N    = 8192;     // nodes
constexpr int NE   = 131072;   // edges
constexpr int WPR  = N / 32;   // 256 u32 words per bitset row
constexpr int MAXD = 64;       // max raw out-degree (Poisson(16); P(>64)*N ~ 1e-15)

// f(k) = exp(-ALPHA*k), ALPHA = 2
#define F1 0.13533528323661270f   // e^-2
#define F2 0.018315638888734179f  // e^-4
#define F3 0.0024787521766663585f // e^-6

using bf16x8 = __attribute__((ext_vector_type(8))) short;
using f32x4  = __attribute__((ext_vector_type(4))) float;

__device__ __forceinline__ unsigned short f2bf(float f) {
    unsigned int u = __float_as_uint(f);
    u = (u + 0x7FFFu + ((u >> 16) & 1u)) >> 16;   // round-to-nearest-even
    return (unsigned short)u;
}

// ---------------------------------------------------------------------------
// Prelude: zero s1+cnt (64 KB) AND convert W0/W1/W2 (fp32 [k][n]) ->
// Wt_g (bf16 [layer][n][k]).  No adj bitmap anymore: dedup is unnecessary
// because every consumer of the CSR is a set-union (re-OR of duplicates is
// idempotent); s1 uses the raw edge list by design.
// ---------------------------------------------------------------------------
__global__ __launch_bounds__(256) void prelude(
    const float* __restrict__ W0, const float* __restrict__ W1,
    const float* __restrict__ W2, unsigned short* __restrict__ Wt_g,
    uint4* __restrict__ zbase)
{
    int gt = blockIdx.x * 256 + threadIdx.x;      // 0 .. 49151
    if (gt < 4096) zbase[gt] = (uint4){0u, 0u, 0u, 0u};   // 64 KB

    int l = gt >> 14;
    int r = gt & 16383;
    int k = r >> 7;
    int n = r & 127;
    const float* W = (l == 0) ? W0 : (l == 1) ? W1 : W2;
    Wt_g[l * 16384 + n * 128 + k] = f2bf(W[k * 128 + n]);
}

// ---------------------------------------------------------------------------
// Fused MLP on matrix cores (R7 form, verified at absmax 0.25).
// C/D layout (m89-verified): col = lane&15, row = (lane>>4)*4 + reg.
// A: [m=lane&15][k=(lane>>4)*8+j];  B: [k=(lane>>4)*8+j][n=lane&15].
// ---------------------------------------------------------------------------
__global__ __launch_bounds__(256) void mlp_kernel(
    const float* __restrict__ X, const unsigned short* __restrict__ Wt_g,
    const float* __restrict__ W3, float* __restrict__ angles)
{
    __shared__ unsigned short Xb[32 * 136];
    __shared__ unsigned short Wt[128 * 136];
    __shared__ float part[2][32];

    const int tid  = threadIdx.x;
    const int row0 = blockIdx.x * 32;
    const int w  = tid >> 6, l = tid & 63;
    const int mt = w & 1, nh = w >> 1;
    const int lm = l & 15, lq = l >> 4;

    // stage X (fp32 -> bf16), coalesced float4 reads, b64 stores
    for (int q = tid; q < 32 * 32; q += 256) {
        float4 v = *(const float4*)&X[row0 * 128 + q * 4];
        ushort4 b;
        b.x = f2bf(v.x); b.y = f2bf(v.y); b.z = f2bf(v.z); b.w = f2bf(v.w);
        *(ushort4*)&Xb[(q >> 5) * 136 + (q & 31) * 4] = b;
    }

    for (int layer = 0; layer < 3; ++layer) {
        // stage W^T bf16 (32 KB) from global, coalesced 16-B chunks
        const unsigned short* Wg = Wt_g + layer * 16384;
        for (int q = tid; q < 2048; q += 256) {
            int n = q >> 4, ck = (q & 15) * 8;
            uint4 v = *(const uint4*)&Wg[n * 128 + ck];
            *(uint4*)&Wt[n * 136 + ck] = v;
        }
        __syncthreads();   // Wt staged; Xb (stage or prev writeback) visible

        f32x4 acc[4];
#pragma unroll
        for (int t = 0; t < 4; ++t) acc[t] = (f32x4){0.f, 0.f, 0.f, 0.f};

#pragma unroll
        for (int kc = 0; kc < 4; ++kc) {
            bf16x8 a = *(const bf16x8*)&Xb[(mt * 16 + lm) * 136 + kc * 32 + lq * 8];
#pragma unroll
            for (int t = 0; t < 4; ++t) {
                bf16x8 b = *(const bf16x8*)
                    &Wt[(nh * 64 + t * 16 + lm) * 136 + kc * 32 + lq * 8];
                acc[t] = __builtin_amdgcn_mfma_f32_16x16x32_bf16(a, b, acc[t], 0, 0, 0);
            }
        }

        // relu
#pragma unroll
        for (int t = 0; t < 4; ++t)
#pragma unroll
            for (int r = 0; r < 4; ++r) acc[t][r] = fmaxf(acc[t][r], 0.0f);

        __syncthreads();   // all waves done reading Xb/Wt before overwrite

        if (layer < 2) {
            // writeback h -> Xb (bf16), C-layout scatter (b16 stores)
#pragma unroll
            for (int t = 0; t < 4; ++t)
#pragma unroll
                for (int r = 0; r < 4; ++r)
                    Xb[(mt * 16 + lq * 4 + r) * 136 + nh * 64 + t * 16 + lm] =
                        f2bf(acc[t][r]);
        } else {
            // fused W3 dot: partial over this wave's 64 cols, fp32
            float p[4] = {0.f, 0.f, 0.f, 0.f};
#pragma unroll
            for (int t = 0; t < 4; ++t) {
                float w3v = W3[nh * 64 + t * 16 + lm];
#pragma unroll
                for (int r = 0; r < 4; ++r) p[r] += acc[t][r] * w3v;
            }
#pragma unroll
            for (int r = 0; r < 4; ++r) {
                p[r] += __shfl_xor(p[r], 1, 64);
                p[r] += __shfl_xor(p[r], 2, 64);
                p[r] += __shfl_xor(p[r], 4, 64);
                p[r] += __shfl_xor(p[r], 8, 64);
            }
            if (lm == 0)
#pragma unroll
                for (int r = 0; r < 4; ++r)
                    part[nh][mt * 16 + lq * 4 + r] = p[r];
            __syncthreads();
            if (tid < 32) angles[row0 + tid] = part[0][tid] + part[1][tid];
        }
    }
}

// ---------------------------------------------------------------------------
// Edge pass: raw CSR build (duplicates KEPT — every consumer is a set-union,
// so re-OR of a duplicate neighbor is idempotent) + hop-1 s1 scatter over
// the RAW edge list (duplicates counted, per reference).
// ---------------------------------------------------------------------------
__global__ void edges_kernel(const int* __restrict__ ei,
                             const float* __restrict__ angles,
                             float* __restrict__ s1,
                             int* __restrict__ cnt_g,
                             int* __restrict__ nbr_g)
{
    int e = blockIdx.x * blockDim.x + threadIdx.x;
    if (e < NE) {
        int r = ei[e];
        int c = ei[NE + e];
        int p = atomicAdd(&cnt_g[r], 1);
        if (p < MAXD) nbr_g[r * MAXD + p] = c;
        atomicAdd(&s1[r], F1 * angles[c]);
    }
}

// ---------------------------------------------------------------------------
// P2 row i = 2-hop union via CSR, built in a per-wave LDS bitmap.
// One wave per row, 4 rows/block. Writes P2 bitmap (stride-64 lane layout) +
// sparse dot vs e1 (= angles+s1, never materialized). Epilogue: s2/e2.
// ---------------------------------------------------------------------------
__global__ __launch_bounds__(256) void p2_kernel(
    const int* __restrict__ cnt_g, const int* __restrict__ nbr_g,
    unsigned int* __restrict__ P2,
    const float* __restrict__ angles, const float* __restrict__ s1,
    float* __restrict__ s2, float* __restrict__ e2)
{
    __shared__ unsigned int bm[4][WPR];  // 4 KB: per-wave bitmap
    __shared__ int nbr[4][MAXD];
    __shared__ int nc[4][MAXD];

    const int wv = threadIdx.x >> 6;
    const int l  = threadIdx.x & 63;
    const int i  = blockIdx.x * 4 + wv;

#pragma unroll
    for (int s = 0; s < 4; ++s) bm[wv][s * 64 + l] = 0u;

    const int n = min(cnt_g[i], MAXD);
    if (l < n) {
        int m = nbr_g[i * MAXD + l];
        nbr[wv][l] = m;
        nc[wv][l]  = min(cnt_g[m], MAXD);
    }
    __syncthreads();

    for (int q = 0; q < n; ++q) {
        int m  = nbr[wv][q];
        int c2 = nc[wv][q];
        if (l < c2) {
            int id = nbr_g[m * MAXD + l];
            atomicOr(&bm[wv][id >> 5], 1u << (id & 31));
        }
    }
    __syncthreads();

    unsigned int w[4];
#pragma unroll
    for (int s = 0; s < 4; ++s) {
        w[s] = bm[wv][s * 64 + l];
        P2[(size_t)i * WPR + s * 64 + l] = w[s];
    }

    // sparse dot: ~4 set bits/lane -> ffs iterate, gather e1 on the fly
    float local = 0.0f;
#pragma unroll
    for (int s = 0; s < 4; ++s) {
        unsigned int ww = w[s];
        const int base = (s * 64 + l) * 32;
        while (ww) {
            int b = __ffs(ww) - 1;
            ww &= ww - 1;
            local += angles[base + b] + s1[base + b];
        }
    }
#pragma unroll
    for (int m = 1; m < 64; m <<= 1) local += __shfl_xor(local, m, 64);
    if (l == 0) {
        float e1i = angles[i] + s1[i];
        float s2v = s1[i] + F2 * local;
        s2[i] = s2v;
        e2[i] = e1i + s2v;
    }
}

// ---------------------------------------------------------------------------
// P3 row i (never materialized) = OR of P2 bitmap rows of i's neighbors.
// out[i] = e2[i] + s2[i] + F3 * (P3[i] . e2)
// One wave per row. Dense dot: 32 chunks; lane l reads float4 e2[c*256+4l]
// (coalesced 1KB/instr); mask nibble fetched from the owning lane with one
// __shfl per chunk (register slot c>>3 is uniform).
// ---------------------------------------------------------------------------
__global__ __launch_bounds__(256) void p3_kernel(
    const unsigned int* __restrict__ P2,
    const int* __restrict__ cnt_g, const int* __restrict__ nbr_g,
    const float* __restrict__ e2, const float* __restrict__ s2,
    float* __restrict__ out)
{
    __shared__ int nbr[4][MAXD];

    const int wv = threadIdx.x >> 6;
    const int l  = threadIdx.x & 63;
    const int i  = blockIdx.x * 4 + wv;

    const int n = min(cnt_g[i], MAXD);
    if (l < n) nbr[wv][l] = nbr_g[i * MAXD + l];
    __syncthreads();

    unsigned int w[4] = {0u, 0u, 0u, 0u};
    for (int q = 0; q < n; ++q) {
        const unsigned int* rowp = P2 + (size_t)nbr[wv][q] * WPR + l;
#pragma unroll
        for (int s = 0; s < 4; ++s) w[s] |= rowp[s * 64];
    }

    float local = 0.0f;
#pragma unroll
    for (int c = 0; c < 32; ++c) {
        unsigned int wd  = __shfl(w[c >> 3], ((c & 7) << 3) | (l >> 3), 64);
        unsigned int nib = wd >> ((l & 7) * 4);
        float4 v = *(const float4*)&e2[c * 256 + l * 4];
        local += (nib & 1u) ? v.x : 0.0f;
        local += (nib & 2u) ? v.y : 0.0f;
        local += (nib & 4u) ? v.z : 0.0f;
        local += (nib & 8u) ? v.w : 0.0f;
    }
#pragma unroll
    for (int m = 1; m < 64; m <<= 1) local += __shfl_xor(local, m, 64);
    if (l == 0)
        out[i] = e2[i] + s2[i] + F3 * local;
}

// ---------------------------------------------------------------------------
// Launch (5 dispatches, all regular — cooperative launch fails under the
// harness's graph capture, see R8 post-mortem)
// ---------------------------------------------------------------------------
extern "C" void kernel_launch(void* const* d_in, const int* in_sizes, int n_in,
                              void* d_out, int out_size, void* d_ws, size_t ws_size,
                              hipStream_t stream)
{
    const float* coeffs = (const float*)d_in[0];
    const float* W0     = (const float*)d_in[1];
    const float* W1     = (const float*)d_in[2];
    const float* W2     = (const float*)d_in[3];
    const float* W3     = (const float*)d_in[4];
    const int*   ei     = (const int*)  d_in[5];
    float* out = (float*)d_out;

    char* ws = (char*)d_ws;
    // workspace layout (bytes)
    float*          angles = (float*)(ws + 0 * 32768);            // 32 KB
    float*          s2     = (float*)(ws + 1 * 32768);            // 32 KB
    float*          e2     = (float*)(ws + 2 * 32768);            // 32 KB
    unsigned short* Wt_g   = (unsigned short*)(ws + 4 * 32768);   // 96 KB
    int*            nbr_g  = (int*)  (ws + (1u  << 20));          // 2 MB
    float*          s1     = (float*)(ws + (4u  << 20));          // 32 KB  (zeroed)
    int*            cnt_g  = (int*)  (ws + (4u  << 20) + 32768);  // 32 KB  (zeroed)
    unsigned int*   P2     = (unsigned int*)(ws + (5u  << 20));   // 8 MB

    // 1) zero s1+cnt (64 KB) AND convert W -> bf16 W^T (one small dispatch)
    prelude<<<192, 256, 0, stream>>>(W0, W1, W2, Wt_g, (uint4*)s1);

    // 2) MFMA MLP
    mlp_kernel<<<N / 32, 256, 0, stream>>>(coeffs, Wt_g, W3, angles);

    // 3-5) graph side (raw CSR, no dedup needed)
    edges_kernel<<<NE / 256, 256, 0, stream>>>(ei, angles, s1, cnt_g, nbr_g);
    p2_kernel<<<N / 4, 256, 0, stream>>>(cnt_g, nbr_g, P2, angles, s1, s2, e2);
    p3_kernel<<<N / 4, 256, 0, stream>>>(P2, cnt_g, nbr_g, e2, s2, out);
}